// Round 1
// baseline (2565.677 us; speedup 1.0000x reference)
//
#include <hip/hip_runtime.h>
#include <cstdint>
#include <cstddef>

#define U4    512   // 4*U
#define UNITS 128
#define BATCH 256
#define TSEQ  512
#define FEAT  64

// ---------------- fast activations (fp32, ~1e-7 rel err) ----------------
__device__ __forceinline__ float sigm(float x) {
    float e = __expf(-x);
    return __fdividef(1.0f, 1.0f + e);
}
__device__ __forceinline__ float tanh_fast(float x) {
    // tanh(x) = 1 - 2/(e^{2x}+1); saturates correctly for |x| large (inf -> 1, 0 -> -1)
    float e = __expf(2.0f * x);
    return 1.0f - __fdividef(2.0f, e + 1.0f);
}

// ---------------- projection GEMM ----------------
// out[M x 512] = in[M x K] @ W[K x 512] + bias
// M = BATCH * Tc, row rg -> (b = rg>>tcShift, tc = rg & (Tc-1)),
// in element: in[b*sB + (t0+tc)*sT + k]
// Tile: 64 rows x 128 cols per block, 256 threads, per-thread 8x4 accs, K panels of 32.
__global__ __launch_bounds__(256, 4)
void proj_gemm(const float* __restrict__ in, const float* __restrict__ W,
               const float* __restrict__ bias, float* __restrict__ out,
               int K, int sB, int sT, int t0, int tcShift)
{
    const int tid = threadIdx.x;
    const int tx = tid & 31;          // col group: cols tx*4 .. tx*4+3
    const int ty = tid >> 5;          // row group: rows ty*8 .. ty*8+7
    const int m0 = blockIdx.x * 64;
    const int n0 = blockIdx.y * 128;
    const int TcMask = (1 << tcShift) - 1;

    __shared__ float As[32][68];      // [k][row], stride 68 keeps float4 reads 16B-aligned
    __shared__ float Bs[32][128];     // [k][col]

    float4 acc[8];
    #pragma unroll
    for (int i = 0; i < 8; ++i) acc[i] = make_float4(0.f, 0.f, 0.f, 0.f);

    for (int k0 = 0; k0 < K; k0 += 32) {
        // A panel: 64 rows x 32 k (scalar coalesced loads, transposed store)
        #pragma unroll
        for (int i = 0; i < 8; ++i) {
            int l = i * 256 + tid;
            int row = l >> 5, kk = l & 31;
            int rg = m0 + row;
            int b = rg >> tcShift, tc = rg & TcMask;
            As[kk][row] = in[(size_t)b * sB + (size_t)(t0 + tc) * sT + k0 + kk];
        }
        // B panel: 32 k x 128 cols (float4 coalesced)
        #pragma unroll
        for (int i = 0; i < 4; ++i) {
            int l = i * 256 + tid;
            int kk = l >> 5, jq = l & 31;
            float4 w4 = *(const float4*)(W + (size_t)(k0 + kk) * U4 + n0 + jq * 4);
            *(float4*)(&Bs[kk][jq * 4]) = w4;
        }
        __syncthreads();
        #pragma unroll
        for (int kk = 0; kk < 32; ++kk) {
            float4 b4 = *(const float4*)(&Bs[kk][tx * 4]);
            float4 a0 = *(const float4*)(&As[kk][ty * 8]);
            float4 a1 = *(const float4*)(&As[kk][ty * 8 + 4]);
            float a[8] = {a0.x, a0.y, a0.z, a0.w, a1.x, a1.y, a1.z, a1.w};
            #pragma unroll
            for (int i = 0; i < 8; ++i) {
                acc[i].x = __builtin_fmaf(a[i], b4.x, acc[i].x);
                acc[i].y = __builtin_fmaf(a[i], b4.y, acc[i].y);
                acc[i].z = __builtin_fmaf(a[i], b4.z, acc[i].z);
                acc[i].w = __builtin_fmaf(a[i], b4.w, acc[i].w);
            }
        }
        __syncthreads();
    }

    float4 bb = *(const float4*)(bias + n0 + tx * 4);
    #pragma unroll
    for (int i = 0; i < 8; ++i) {
        int rg = m0 + ty * 8 + i;
        float4 v = acc[i];
        v.x += bb.x; v.y += bb.y; v.z += bb.z; v.w += bb.w;
        *(float4*)(out + (size_t)rg * U4 + n0 + tx * 4) = v;
    }
}

// ---------------- LSTM recurrence ----------------
// One block per batch row; 512 threads, thread j owns gate-column j.
// R[128][512] held in VGPRs (128 regs/thread). h broadcast via v_readlane
// (SGPR operand on the FMA) -> only 2 LDS reads per wave per step.
__global__ __launch_bounds__(512, 2)
void lstm_rec(const float* __restrict__ xw, const float* __restrict__ R,
              float* __restrict__ h_state, float* __restrict__ c_state,
              float* __restrict__ h_out, int Tc, int init)
{
    const int j = threadIdx.x;
    const int b = blockIdx.x;
    const int lane = j & 63;

    __shared__ float lds_h[UNITS];
    __shared__ float lds_z[U4];

    // R columns into registers: Rreg[k] = R[k][j]
    float Rreg[UNITS];
    #pragma unroll
    for (int k = 0; k < UNITS; ++k) Rreg[k] = R[(size_t)k * U4 + j];

    float c = 0.f;
    if (j < UNITS) {
        float h0 = 0.f;
        if (!init) {
            h0 = h_state[b * UNITS + j];
            c  = c_state[b * UNITS + j];
        }
        lds_h[j] = h0;
    }
    __syncthreads();

    const float* xwB = xw + (size_t)b * Tc * U4;
    float xwc = xwB[j];

    #pragma unroll 1
    for (int t = 0; t < Tc; ++t) {
        // prefetch next step's xw early (hidden behind the FMA chain)
        int tn = (t + 1 < Tc) ? (t + 1) : t;
        float xwn = xwB[(size_t)tn * U4 + j];

        // per-wave copy of h: lane k holds h[k] (vh0) and h[64+k] (vh1)
        float vh0 = lds_h[lane];
        float vh1 = lds_h[lane + 64];

        float z0 = xwc, z1 = 0.f;   // two chains to halve FMA dep latency
        #pragma unroll
        for (int k = 0; k < 64; ++k) {
            float h0 = __int_as_float(__builtin_amdgcn_readlane(__float_as_int(vh0), k));
            float h1 = __int_as_float(__builtin_amdgcn_readlane(__float_as_int(vh1), k));
            z0 = __builtin_fmaf(h0, Rreg[k], z0);
            z1 = __builtin_fmaf(h1, Rreg[64 + k], z1);
        }
        float zj = z0 + z1;

        // activation by gate class (wave-uniform branches: waves 0-3 sigm, 4-5 tanh, 6-7 sigm)
        float a;
        if (j < 256)      a = sigm(zj);       // i, f
        else if (j < 384) a = tanh_fast(zj);  // g
        else              a = sigm(zj);       // o
        lds_z[j] = a;
        __syncthreads();

        if (j < UNITS) {
            float iv = lds_z[j];
            float fv = lds_z[j + 128];
            float gv = lds_z[j + 256];
            float ov = lds_z[j + 384];
            c = __builtin_fmaf(fv, c, iv * gv);
            float hv = ov * tanh_fast(c);
            lds_h[j] = hv;
            if (h_out) h_out[((size_t)b * Tc + t) * UNITS + j] = hv;
        }
        __syncthreads();
        xwc = xwn;
    }

    if (j < UNITS) {
        h_state[b * UNITS + j] = lds_h[j];
        c_state[b * UNITS + j] = c;
    }
}

// ---------------- dense head ----------------
// out[256][6] = h2[256][128] @ Wd[128][6] + bd
__global__ __launch_bounds__(256)
void dense_head(const float* __restrict__ h2, const float* __restrict__ Wd,
                const float* __restrict__ bd, float* __restrict__ out)
{
    int b = threadIdx.x;
    float acc[6];
    #pragma unroll
    for (int o = 0; o < 6; ++o) acc[o] = bd[o];
    #pragma unroll 4
    for (int k = 0; k < UNITS; ++k) {
        float hv = h2[b * UNITS + k];
        #pragma unroll
        for (int o = 0; o < 6; ++o)
            acc[o] = __builtin_fmaf(hv, Wd[k * 6 + o], acc[o]);
    }
    #pragma unroll
    for (int o = 0; o < 6; ++o) out[b * 6 + o] = acc[o];
}

extern "C" void kernel_launch(void* const* d_in, const int* in_sizes, int n_in,
                              void* d_out, int out_size, void* d_ws, size_t ws_size,
                              hipStream_t stream)
{
    (void)in_sizes; (void)n_in; (void)out_size;
    const float* x  = (const float*)d_in[0];
    const float* Ws[3] = {(const float*)d_in[1], (const float*)d_in[4], (const float*)d_in[7]};
    const float* Rs[3] = {(const float*)d_in[2], (const float*)d_in[5], (const float*)d_in[8]};
    const float* bs[3] = {(const float*)d_in[3], (const float*)d_in[6], (const float*)d_in[9]};
    const float* Wd = (const float*)d_in[10];
    const float* bd = (const float*)d_in[11];
    float* out = (float*)d_out;

    // choose largest chunk Tc in {128,64,32,16,8,4} that fits the workspace
    int tcShift = 7;
    while (tcShift > 2) {
        size_t need = ((size_t)1 << tcShift) * 655360u + 786432u;
        if (need <= ws_size) break;
        --tcShift;
    }
    const int Tc = 1 << tcShift;

    float* xw = (float*)d_ws;                                // [B][Tc][512]
    float* hc = xw + (size_t)BATCH * Tc * U4;                // [B][Tc][128]
    float* hs = hc + (size_t)BATCH * Tc * UNITS;             // 3 x [B][128]
    float* cs = hs + 3 * BATCH * UNITS;                      // 3 x [B][128]

    const int nChunks = TSEQ / Tc;
    for (int ch = 0; ch < nChunks; ++ch) {
        const int t0 = ch * Tc;
        for (int layer = 0; layer < 3; ++layer) {
            const float* in = (layer == 0) ? x : hc;
            const int K  = (layer == 0) ? FEAT : UNITS;
            const int sB = (layer == 0) ? TSEQ * FEAT : Tc * UNITS;
            const int sT = K;
            const int pt0 = (layer == 0) ? t0 : 0;

            dim3 grid(BATCH * Tc / 64, 4);
            proj_gemm<<<grid, 256, 0, stream>>>(in, Ws[layer], bs[layer], xw,
                                                K, sB, sT, pt0, tcShift);

            float* hOut = (layer < 2) ? hc : nullptr;
            lstm_rec<<<BATCH, 512, 0, stream>>>(xw, Rs[layer],
                                                hs + layer * BATCH * UNITS,
                                                cs + layer * BATCH * UNITS,
                                                hOut, Tc, (ch == 0) ? 1 : 0);
        }
    }
    dense_head<<<1, 256, 0, stream>>>(hs + 2 * BATCH * UNITS, Wd, bd, out);
}